// Round 1
// baseline (17.291 us; speedup 1.0000x reference)
//
#include <hip/hip_runtime.h>

// half_integer_2bit_8col: per-row nearest-codeword quantization to the
// E8-like half-integer codebook {c_i in {0.5,1.5,2.5,3.5}, ||c||^2 <= 10}.
//
// Structure of the codebook (derivation):
//   base all-0.5 has ||.||^2 = 2. Upgrading 0.5->1.5 adds 2, 1.5->2.5 adds 4,
//   2.5->3.5 adds 6 to the norm; budget is 8. Hence valid codewords are:
//     (A) <=4 components at 1.5, rest 0.5          [163 codewords]
//     (B) one component at 2.5, <=1 other at 1.5   [ 64 codewords]
//   163 + 64 = 227 = |grid_part|  (3.5 never appears).
//
// argmax_g 2<x,g> - ||g||^2 decomposes into independent upgrade gains:
//   0.5->1.5 on i: 2(x_i - 1);  1.5->2.5 on i: additional 2(x_i - 2).
// Optimal config is max of:
//   A* = 2 * sum of top-<=4 positive (x_i - 1)
//   B* = (4*y1 - 6) + 2*max(0, y2 - 1)   (y1,y2 = two largest |x|)
//
// Rank (index into lexicographically sorted grid) is looked up via a
// base-3 keyed LDS LUT built from grid_part itself each block.

constexpr int CODESZ = 8;
constexpr int NGRID  = 227;
constexpr int NKEYS  = 6561;  // 3^8

__global__ __launch_bounds__(256, 8)
void hi2b_kernel(const float* __restrict__ X,
                 const float* __restrict__ grid_part,
                 float* __restrict__ out_vals,
                 float* __restrict__ out_idxs,
                 int n_rows, int rows_per_block)
{
    __shared__ unsigned short s_lut[NKEYS];
    const int t = threadIdx.x;

    // Build codeword-digits -> rank LUT from grid_part (it is already sorted;
    // row r has rank r). Digits: (int)v for v in {0.5,1.5,2.5} -> {0,1,2}.
    if (t < NGRID) {
        const float* g = grid_part + t * CODESZ;
        int key = 0, p3 = 1;
#pragma unroll
        for (int i = 0; i < CODESZ; ++i) {
            key += (int)g[i] * p3;
            p3 *= 3;
        }
        s_lut[key] = (unsigned short)t;
    }
    __syncthreads();

    const int base = blockIdx.x * rows_per_block;

    for (int r0 = 0; r0 < rows_per_block; r0 += 256) {
        const int row = base + r0 + t;
        if (row < n_rows) {
            const float4* xp = reinterpret_cast<const float4*>(X + (size_t)row * CODESZ);
            float4 va = xp[0];
            float4 vb = xp[1];
            float x[8] = {va.x, va.y, va.z, va.w, vb.x, vb.y, vb.z, vb.w};

            int flips = 0;
            float ax[8];
            unsigned pk[8];
#pragma unroll
            for (int i = 0; i < 8; ++i) {
                int neg = (x[i] < 0.0f) ? 1 : 0;
                flips |= neg << i;
                float a = fabsf(x[i]);
                ax[i] = a;
                // pack lane index into low 3 mantissa bits: unsigned compare
                // preserves float order on non-negative floats, keys unique.
                pk[i] = (__float_as_uint(a) & 0xFFFFFFF8u) | (unsigned)i;
            }

            // Sort a copy descending: 19-comparator optimal network for 8.
            unsigned s0 = pk[0], s1 = pk[1], s2 = pk[2], s3 = pk[3];
            unsigned s4 = pk[4], s5 = pk[5], s6 = pk[6], s7 = pk[7];
#define CASD(a, b) { unsigned _hi = (a) > (b) ? (a) : (b); unsigned _lo = (a) > (b) ? (b) : (a); (a) = _hi; (b) = _lo; }
            CASD(s0, s1) CASD(s2, s3) CASD(s4, s5) CASD(s6, s7)
            CASD(s0, s2) CASD(s1, s3) CASD(s4, s6) CASD(s5, s7)
            CASD(s1, s2) CASD(s5, s6) CASD(s0, s4) CASD(s3, s7)
            CASD(s1, s5) CASD(s2, s6)
            CASD(s1, s4) CASD(s3, s6)
            CASD(s2, s4) CASD(s3, s5)
            CASD(s3, s4)
#undef CASD

            const float y1 = __uint_as_float(s0 & 0xFFFFFFF8u);
            const float y2 = __uint_as_float(s1 & 0xFFFFFFF8u);
            const float y3 = __uint_as_float(s2 & 0xFFFFFFF8u);
            const float y4 = __uint_as_float(s3 & 0xFFFFFFF8u);
            const float t1 = fmaxf(y1 - 1.0f, 0.0f);
            const float t2 = fmaxf(y2 - 1.0f, 0.0f);
            const float t3 = fmaxf(y3 - 1.0f, 0.0f);
            const float t4 = fmaxf(y4 - 1.0f, 0.0f);
            const float Ap = (t1 + t2) + (t3 + t4);     // = A*/2
            const float Bp = 2.0f * y1 - 3.0f + t2;     // = B*/2
            const bool useB = Bp > Ap;

            int key = 0;
            float ov[8];
            int p3 = 1;
#pragma unroll
            for (int i = 0; i < 8; ++i) {
                const bool gt1 = ax[i] > 1.0f;
                const int dA = (pk[i] >= s3 && gt1) ? 1 : 0;            // in top-4 and gain>0
                const int dB = (pk[i] == s0) ? 2 : ((pk[i] == s1 && gt1) ? 1 : 0);
                const int d  = useB ? dB : dA;
                key += d * p3;
                p3 *= 3;
                float v = 0.5f + (float)d;
                ov[i] = ((flips >> i) & 1) ? -v : v;
            }

            const int rank = s_lut[key];

            float4* op = reinterpret_cast<float4*>(out_vals + (size_t)row * CODESZ);
            op[0] = make_float4(ov[0], ov[1], ov[2], ov[3]);
            op[1] = make_float4(ov[4], ov[5], ov[6], ov[7]);
            out_idxs[row] = (float)((flips << 8) + rank - 32768);
        }
    }
}

extern "C" void kernel_launch(void* const* d_in, const int* in_sizes, int n_in,
                              void* d_out, int out_size, void* d_ws, size_t ws_size,
                              hipStream_t stream) {
    const float* X         = (const float*)d_in[0];
    const float* grid_part = (const float*)d_in[1];
    // d_in[2] = grid_part_norm, d_in[3] = int_map: not needed (closed-form).

    const int n_rows = in_sizes[0] / CODESZ;

    float* out_vals = (float*)d_out;
    float* out_idxs = out_vals + (size_t)n_rows * CODESZ;

    const int blocks = 2048;
    const int rows_per_block = (n_rows + blocks - 1) / blocks;  // 512 for 1M rows

    hi2b_kernel<<<blocks, 256, 0, stream>>>(X, grid_part, out_vals, out_idxs,
                                            n_rows, rows_per_block);
}